// Round 5
// baseline (318.455 us; speedup 1.0000x reference)
//
#include <hip/hip_runtime.h>

// NEAT batched forward, occupancy edition.
// R3 was critical-path bound (no pipe >20% busy, occupancy 32%). Fix: shrink LDS
// 36.3KB -> 17.7KB (packed 6B edges, capacity 2560 instead of 4096) and cap VGPR
// at 64 via __launch_bounds__(256,8) -> 8 blocks/CU resident (was ~4).
// Edge bucketing by target-layer via wave ballots; block-uniform fallback path
// guarantees correctness if live edges ever exceed CAP (never on random data).

#define NN    256
#define NE    4096
#define NIN   64
#define NOUT  8
#define NT    256
#define NWAVE 4
#define CAP   2560   // live-edge capacity: E[live]=1536, sd=31 -> 33 sigma margin

__global__ __launch_bounds__(NT, 8) void neat_fwd(
    const float* __restrict__ inputs,          // [B,64]
    const int*   __restrict__ node_layer,      // [B,256]
    const int*   __restrict__ conn_in,         // [B,4096]
    const int*   __restrict__ conn_out,        // [B,4096]
    const float* __restrict__ conn_w,          // [B,4096]
    const unsigned char* __restrict__ conn_en, // [B,4096] bool (layout sniffed)
    float*       __restrict__ out)             // [B,8]
{
    const int b    = blockIdx.x;
    const int t    = threadIdx.x;
    const int wave = t >> 6;
    const int lane = t & 63;
    const unsigned long long lmlt = (1ull << lane) - 1ull;

    __shared__ float          vals[NN];
    __shared__ float          agg[NN];
    __shared__ unsigned char  nl_sh[NN];
    __shared__ float          ew[CAP];          // edge weight
    __shared__ unsigned short ep[CAP];          // src | (tgt<<8)
    __shared__ int            wave_cnt[NWAVE][3];

    // --- sniff conn_enabled element width (uniform): byte bools vs int32 ---
    const unsigned int* en_w = (const unsigned int*)conn_en;
    bool byte_mode = false;
#pragma unroll
    for (int i = 0; i < 16; ++i) byte_mode |= (en_w[i] > 1u);

    // --- init LDS state ---
    const int nl = node_layer[(size_t)b * NN + t];
    nl_sh[t] = (unsigned char)nl;
    vals[t]  = (t < NIN) ? inputs[(size_t)b * NIN + t] : 0.0f;
    agg[t]   = 0.0f;

    // --- load 16 connections into NAMED registers (coalesced 16B vec loads) ---
    const int4*   ci4 = (const int4*)(conn_in  + (size_t)b * NE);
    const int4*   co4 = (const int4*)(conn_out + (size_t)b * NE);
    const float4* w4  = (const float4*)(conn_w  + (size_t)b * NE);

    int4 a0 = ci4[t       ];
    int4 a1 = ci4[t + 1*NT];
    int4 a2 = ci4[t + 2*NT];
    int4 a3 = ci4[t + 3*NT];
    int4 c0 = co4[t       ];
    int4 c1 = co4[t + 1*NT];
    int4 c2 = co4[t + 2*NT];
    int4 c3 = co4[t + 3*NT];
    float4 w0 = w4[t       ];
    float4 w1 = w4[t + 1*NT];
    float4 w2 = w4[t + 2*NT];
    float4 w3 = w4[t + 3*NT];

    unsigned m = 0;
    if (byte_mode) {
        const uchar4* e4 = (const uchar4*)(conn_en + (size_t)b * NE);
        uchar4 e0 = e4[t       ];
        uchar4 e1 = e4[t + 1*NT];
        uchar4 e2 = e4[t + 2*NT];
        uchar4 e3 = e4[t + 3*NT];
        m = (e0.x ? 1u<<0  : 0u) | (e0.y ? 1u<<1  : 0u) | (e0.z ? 1u<<2  : 0u) | (e0.w ? 1u<<3  : 0u)
          | (e1.x ? 1u<<4  : 0u) | (e1.y ? 1u<<5  : 0u) | (e1.z ? 1u<<6  : 0u) | (e1.w ? 1u<<7  : 0u)
          | (e2.x ? 1u<<8  : 0u) | (e2.y ? 1u<<9  : 0u) | (e2.z ? 1u<<10 : 0u) | (e2.w ? 1u<<11 : 0u)
          | (e3.x ? 1u<<12 : 0u) | (e3.y ? 1u<<13 : 0u) | (e3.z ? 1u<<14 : 0u) | (e3.w ? 1u<<15 : 0u);
    } else {
        const int4* e4 = (const int4*)((const int*)conn_en + (size_t)b * NE);
        int4 e0 = e4[t       ];
        int4 e1 = e4[t + 1*NT];
        int4 e2 = e4[t + 2*NT];
        int4 e3 = e4[t + 3*NT];
        m = (e0.x ? 1u<<0  : 0u) | (e0.y ? 1u<<1  : 0u) | (e0.z ? 1u<<2  : 0u) | (e0.w ? 1u<<3  : 0u)
          | (e1.x ? 1u<<4  : 0u) | (e1.y ? 1u<<5  : 0u) | (e1.z ? 1u<<6  : 0u) | (e1.w ? 1u<<7  : 0u)
          | (e2.x ? 1u<<8  : 0u) | (e2.y ? 1u<<9  : 0u) | (e2.z ? 1u<<10 : 0u) | (e2.w ? 1u<<11 : 0u)
          | (e3.x ? 1u<<12 : 0u) | (e3.y ? 1u<<13 : 0u) | (e3.z ? 1u<<14 : 0u) | (e3.w ? 1u<<15 : 0u);
    }
    __syncthreads();   // nl_sh / vals / agg ready

    // --- per-edge key = enabled ? layer(target) : 0 ; per-wave counts ---
    unsigned keys = 0;
    int c1n = 0, c2n = 0, c3n = 0;
#define KEYSLOT(J, CO) { \
        int kk = (int)nl_sh[(CO)]; \
        kk = ((m >> (J)) & 1u) ? kk : 0; \
        keys |= (unsigned)kk << (2*(J)); \
        c1n += (kk == 1); c2n += (kk == 2); c3n += (kk == 3); }
    KEYSLOT(0,  c0.x) KEYSLOT(1,  c0.y) KEYSLOT(2,  c0.z) KEYSLOT(3,  c0.w)
    KEYSLOT(4,  c1.x) KEYSLOT(5,  c1.y) KEYSLOT(6,  c1.z) KEYSLOT(7,  c1.w)
    KEYSLOT(8,  c2.x) KEYSLOT(9,  c2.y) KEYSLOT(10, c2.z) KEYSLOT(11, c2.w)
    KEYSLOT(12, c3.x) KEYSLOT(13, c3.y) KEYSLOT(14, c3.z) KEYSLOT(15, c3.w)
#undef KEYSLOT

#pragma unroll
    for (int off = 32; off > 0; off >>= 1) {
        c1n += __shfl_down(c1n, off);
        c2n += __shfl_down(c2n, off);
        c3n += __shfl_down(c3n, off);
    }
    if (lane == 0) {
        wave_cnt[wave][0] = c1n;
        wave_cnt[wave][1] = c2n;
        wave_cnt[wave][2] = c3n;
    }
    __syncthreads();

    // --- redundant per-thread scan (LDS broadcast reads; no extra barrier) ---
    int T1 = 0, T2 = 0, T3 = 0, p1 = 0, p2 = 0, p3 = 0;
#pragma unroll
    for (int w = 0; w < NWAVE; ++w) {
        const int x = wave_cnt[w][0], y = wave_cnt[w][1], z = wave_cnt[w][2];
        if (w < wave) { p1 += x; p2 += y; p3 += z; }
        T1 += x; T2 += y; T3 += z;
    }
    const int total = T1 + T2 + T3;

    if (total <= CAP) {
        // ---------------- fast path: bucketed edges ----------------
        int base1 = p1;
        int base2 = T1 + p2;
        int base3 = T1 + T2 + p3;
#define SCAT(J, CI, CO, W) { \
        int kk = (int)((keys >> (2*(J))) & 3u); \
        unsigned long long B1 = __ballot(kk == 1); \
        unsigned long long B2 = __ballot(kk == 2); \
        unsigned long long B3 = __ballot(kk == 3); \
        if (kk) { \
            unsigned long long bk = (kk == 1) ? B1 : ((kk == 2) ? B2 : B3); \
            int bs = (kk == 1) ? base1 : ((kk == 2) ? base2 : base3); \
            int pos = bs + __popcll(bk & lmlt); \
            ew[pos] = (W); \
            ep[pos] = (unsigned short)((unsigned)(CI) | ((unsigned)(CO) << 8)); \
        } \
        base1 += __popcll(B1); base2 += __popcll(B2); base3 += __popcll(B3); }
        SCAT(0,  a0.x, c0.x, w0.x) SCAT(1,  a0.y, c0.y, w0.y)
        SCAT(2,  a0.z, c0.z, w0.z) SCAT(3,  a0.w, c0.w, w0.w)
        SCAT(4,  a1.x, c1.x, w1.x) SCAT(5,  a1.y, c1.y, w1.y)
        SCAT(6,  a1.z, c1.z, w1.z) SCAT(7,  a1.w, c1.w, w1.w)
        SCAT(8,  a2.x, c2.x, w2.x) SCAT(9,  a2.y, c2.y, w2.y)
        SCAT(10, a2.z, c2.z, w2.z) SCAT(11, a2.w, c2.w, w2.w)
        SCAT(12, a3.x, c3.x, w3.x) SCAT(13, a3.y, c3.y, w3.y)
        SCAT(14, a3.z, c3.z, w3.z) SCAT(15, a3.w, c3.w, w3.w)
#undef SCAT
        __syncthreads();   // edges ready

        float vreg = vals[t];
#pragma unroll
        for (int L = 1; L < 4; ++L) {
            const int s = (L == 1) ? 0  : ((L == 2) ? T1 : T1 + T2);
            const int e = (L == 1) ? T1 : ((L == 2) ? T1 + T2 : total);
            for (int p = s + t; p < e; p += NT) {
                const unsigned pk = ep[p];
                atomicAdd(&agg[pk >> 8], vals[pk & 0xFFu] * ew[p]);
            }
            __syncthreads();
            const float u = agg[t];
            if (nl == L) { vreg = tanhf(u); vals[t] = vreg; }
            agg[t] = 0.0f;
            if (L < 3) __syncthreads();
        }
        if (t >= NIN && t < NIN + NOUT)
            out[(size_t)b * NOUT + (t - NIN)] = vreg;
    } else {
        // ------- slow path (never taken on random data): reg-edge atomics -------
        float vreg = vals[t];
#pragma unroll
        for (int L = 1; L < 4; ++L) {
#define FB(J, CI, CO, W) \
            if (((keys >> (2*(J))) & 3u) == (unsigned)L) atomicAdd(&agg[(CO)], vals[(CI)] * (W));
            FB(0,  a0.x, c0.x, w0.x) FB(1,  a0.y, c0.y, w0.y)
            FB(2,  a0.z, c0.z, w0.z) FB(3,  a0.w, c0.w, w0.w)
            FB(4,  a1.x, c1.x, w1.x) FB(5,  a1.y, c1.y, w1.y)
            FB(6,  a1.z, c1.z, w1.z) FB(7,  a1.w, c1.w, w1.w)
            FB(8,  a2.x, c2.x, w2.x) FB(9,  a2.y, c2.y, w2.y)
            FB(10, a2.z, c2.z, w2.z) FB(11, a2.w, c2.w, w2.w)
            FB(12, a3.x, c3.x, w3.x) FB(13, a3.y, c3.y, w3.y)
            FB(14, a3.z, c3.z, w3.z) FB(15, a3.w, c3.w, w3.w)
#undef FB
            __syncthreads();
            const float u = agg[t];
            if (nl == L) { vreg = tanhf(u); vals[t] = vreg; }
            agg[t] = 0.0f;
            if (L < 3) __syncthreads();
        }
        if (t >= NIN && t < NIN + NOUT)
            out[(size_t)b * NOUT + (t - NIN)] = vreg;
    }
}

extern "C" void kernel_launch(void* const* d_in, const int* in_sizes, int n_in,
                              void* d_out, int out_size, void* d_ws, size_t ws_size,
                              hipStream_t stream) {
    const float* inputs          = (const float*)d_in[0];
    const int*   node_layer      = (const int*)d_in[1];
    const int*   conn_in         = (const int*)d_in[2];
    const int*   conn_out        = (const int*)d_in[3];
    const float* conn_w          = (const float*)d_in[4];
    const unsigned char* conn_en = (const unsigned char*)d_in[5];
    float* out = (float*)d_out;

    const int B = in_sizes[0] / NIN;   // 4096
    neat_fwd<<<B, NT, 0, stream>>>(inputs, node_layer, conn_in, conn_out,
                                   conn_w, conn_en, out);
}

// Round 6
// 251.353 us; speedup vs baseline: 1.2670x; 1.2670x over previous
//
#include <hip/hip_runtime.h>

// NEAT batched forward, occupancy edition v2.
// R5 lesson: __launch_bounds__(256,8) forced VGPR<=64 -> compiler spilled the 12
// named edge registers to scratch (WRITE_SIZE 0.1->147MB, dur 108->170us).
// Fix: plain __launch_bounds__(256). VGPR ~52 (R3-measured) x 8 waves = 448 <= 512,
// LDS 17.9KB -> 8 blocks/CU reachable with NO spills.
// Structure: bucket edges by target-layer once (wave ballots), visit each live
// edge exactly once; in_count mask provably redundant (tanh(0)==0).

#define NN    256
#define NE    4096
#define NIN   64
#define NOUT  8
#define NT    256
#define NWAVE 4
#define CAP   2560   // live-edge capacity: E[live]=1536, sd=31 -> 33 sigma margin

__global__ __launch_bounds__(NT) void neat_fwd(
    const float* __restrict__ inputs,          // [B,64]
    const int*   __restrict__ node_layer,      // [B,256]
    const int*   __restrict__ conn_in,         // [B,4096]
    const int*   __restrict__ conn_out,        // [B,4096]
    const float* __restrict__ conn_w,          // [B,4096]
    const unsigned char* __restrict__ conn_en, // [B,4096] bool (layout sniffed)
    float*       __restrict__ out)             // [B,8]
{
    const int b    = blockIdx.x;
    const int t    = threadIdx.x;
    const int wave = t >> 6;
    const int lane = t & 63;
    const unsigned long long lmlt = (1ull << lane) - 1ull;

    __shared__ float          vals[NN];
    __shared__ float          agg[NN];
    __shared__ unsigned char  nl_sh[NN];
    __shared__ float          ew[CAP];          // edge weight
    __shared__ unsigned short ep[CAP];          // src | (tgt<<8)
    __shared__ int            wave_cnt[NWAVE][3];

    // --- sniff conn_enabled element width (uniform): byte bools vs int32 ---
    const unsigned int* en_w = (const unsigned int*)conn_en;
    bool byte_mode = false;
#pragma unroll
    for (int i = 0; i < 16; ++i) byte_mode |= (en_w[i] > 1u);

    // --- init LDS state ---
    const int nl = node_layer[(size_t)b * NN + t];
    nl_sh[t] = (unsigned char)nl;
    vals[t]  = (t < NIN) ? inputs[(size_t)b * NIN + t] : 0.0f;
    agg[t]   = 0.0f;

    // --- load 16 connections into NAMED registers (coalesced 16B vec loads) ---
    const int4*   ci4 = (const int4*)(conn_in  + (size_t)b * NE);
    const int4*   co4 = (const int4*)(conn_out + (size_t)b * NE);
    const float4* w4  = (const float4*)(conn_w  + (size_t)b * NE);

    int4 a0 = ci4[t       ];
    int4 a1 = ci4[t + 1*NT];
    int4 a2 = ci4[t + 2*NT];
    int4 a3 = ci4[t + 3*NT];
    int4 c0 = co4[t       ];
    int4 c1 = co4[t + 1*NT];
    int4 c2 = co4[t + 2*NT];
    int4 c3 = co4[t + 3*NT];
    float4 w0 = w4[t       ];
    float4 w1 = w4[t + 1*NT];
    float4 w2 = w4[t + 2*NT];
    float4 w3 = w4[t + 3*NT];

    unsigned m = 0;
    if (byte_mode) {
        const uchar4* e4 = (const uchar4*)(conn_en + (size_t)b * NE);
        uchar4 e0 = e4[t       ];
        uchar4 e1 = e4[t + 1*NT];
        uchar4 e2 = e4[t + 2*NT];
        uchar4 e3 = e4[t + 3*NT];
        m = (e0.x ? 1u<<0  : 0u) | (e0.y ? 1u<<1  : 0u) | (e0.z ? 1u<<2  : 0u) | (e0.w ? 1u<<3  : 0u)
          | (e1.x ? 1u<<4  : 0u) | (e1.y ? 1u<<5  : 0u) | (e1.z ? 1u<<6  : 0u) | (e1.w ? 1u<<7  : 0u)
          | (e2.x ? 1u<<8  : 0u) | (e2.y ? 1u<<9  : 0u) | (e2.z ? 1u<<10 : 0u) | (e2.w ? 1u<<11 : 0u)
          | (e3.x ? 1u<<12 : 0u) | (e3.y ? 1u<<13 : 0u) | (e3.z ? 1u<<14 : 0u) | (e3.w ? 1u<<15 : 0u);
    } else {
        const int4* e4 = (const int4*)((const int*)conn_en + (size_t)b * NE);
        int4 e0 = e4[t       ];
        int4 e1 = e4[t + 1*NT];
        int4 e2 = e4[t + 2*NT];
        int4 e3 = e4[t + 3*NT];
        m = (e0.x ? 1u<<0  : 0u) | (e0.y ? 1u<<1  : 0u) | (e0.z ? 1u<<2  : 0u) | (e0.w ? 1u<<3  : 0u)
          | (e1.x ? 1u<<4  : 0u) | (e1.y ? 1u<<5  : 0u) | (e1.z ? 1u<<6  : 0u) | (e1.w ? 1u<<7  : 0u)
          | (e2.x ? 1u<<8  : 0u) | (e2.y ? 1u<<9  : 0u) | (e2.z ? 1u<<10 : 0u) | (e2.w ? 1u<<11 : 0u)
          | (e3.x ? 1u<<12 : 0u) | (e3.y ? 1u<<13 : 0u) | (e3.z ? 1u<<14 : 0u) | (e3.w ? 1u<<15 : 0u);
    }
    __syncthreads();   // nl_sh / vals / agg ready

    // --- per-edge key = enabled ? layer(target) : 0 ; per-wave counts ---
    unsigned keys = 0;
    int c1n = 0, c2n = 0, c3n = 0;
#define KEYSLOT(J, CO) { \
        int kk = (int)nl_sh[(CO)]; \
        kk = ((m >> (J)) & 1u) ? kk : 0; \
        keys |= (unsigned)kk << (2*(J)); \
        c1n += (kk == 1); c2n += (kk == 2); c3n += (kk == 3); }
    KEYSLOT(0,  c0.x) KEYSLOT(1,  c0.y) KEYSLOT(2,  c0.z) KEYSLOT(3,  c0.w)
    KEYSLOT(4,  c1.x) KEYSLOT(5,  c1.y) KEYSLOT(6,  c1.z) KEYSLOT(7,  c1.w)
    KEYSLOT(8,  c2.x) KEYSLOT(9,  c2.y) KEYSLOT(10, c2.z) KEYSLOT(11, c2.w)
    KEYSLOT(12, c3.x) KEYSLOT(13, c3.y) KEYSLOT(14, c3.z) KEYSLOT(15, c3.w)
#undef KEYSLOT

#pragma unroll
    for (int off = 32; off > 0; off >>= 1) {
        c1n += __shfl_down(c1n, off);
        c2n += __shfl_down(c2n, off);
        c3n += __shfl_down(c3n, off);
    }
    if (lane == 0) {
        wave_cnt[wave][0] = c1n;
        wave_cnt[wave][1] = c2n;
        wave_cnt[wave][2] = c3n;
    }
    __syncthreads();

    // --- redundant per-thread scan (LDS broadcast reads; no extra barrier) ---
    int T1 = 0, T2 = 0, T3 = 0, p1 = 0, p2 = 0, p3 = 0;
#pragma unroll
    for (int w = 0; w < NWAVE; ++w) {
        const int x = wave_cnt[w][0], y = wave_cnt[w][1], z = wave_cnt[w][2];
        if (w < wave) { p1 += x; p2 += y; p3 += z; }
        T1 += x; T2 += y; T3 += z;
    }
    const int total = T1 + T2 + T3;

    if (total <= CAP) {
        // ---------------- fast path: bucketed edges ----------------
        int base1 = p1;
        int base2 = T1 + p2;
        int base3 = T1 + T2 + p3;
#define SCAT(J, CI, CO, W) { \
        int kk = (int)((keys >> (2*(J))) & 3u); \
        unsigned long long B1 = __ballot(kk == 1); \
        unsigned long long B2 = __ballot(kk == 2); \
        unsigned long long B3 = __ballot(kk == 3); \
        if (kk) { \
            unsigned long long bk = (kk == 1) ? B1 : ((kk == 2) ? B2 : B3); \
            int bs = (kk == 1) ? base1 : ((kk == 2) ? base2 : base3); \
            int pos = bs + __popcll(bk & lmlt); \
            ew[pos] = (W); \
            ep[pos] = (unsigned short)((unsigned)(CI) | ((unsigned)(CO) << 8)); \
        } \
        base1 += __popcll(B1); base2 += __popcll(B2); base3 += __popcll(B3); }
        SCAT(0,  a0.x, c0.x, w0.x) SCAT(1,  a0.y, c0.y, w0.y)
        SCAT(2,  a0.z, c0.z, w0.z) SCAT(3,  a0.w, c0.w, w0.w)
        SCAT(4,  a1.x, c1.x, w1.x) SCAT(5,  a1.y, c1.y, w1.y)
        SCAT(6,  a1.z, c1.z, w1.z) SCAT(7,  a1.w, c1.w, w1.w)
        SCAT(8,  a2.x, c2.x, w2.x) SCAT(9,  a2.y, c2.y, w2.y)
        SCAT(10, a2.z, c2.z, w2.z) SCAT(11, a2.w, c2.w, w2.w)
        SCAT(12, a3.x, c3.x, w3.x) SCAT(13, a3.y, c3.y, w3.y)
        SCAT(14, a3.z, c3.z, w3.z) SCAT(15, a3.w, c3.w, w3.w)
#undef SCAT
        __syncthreads();   // edges ready

        float vreg = vals[t];
#pragma unroll
        for (int L = 1; L < 4; ++L) {
            const int s = (L == 1) ? 0  : ((L == 2) ? T1 : T1 + T2);
            const int e = (L == 1) ? T1 : ((L == 2) ? T1 + T2 : total);
            for (int p = s + t; p < e; p += NT) {
                const unsigned pk = ep[p];
                atomicAdd(&agg[pk >> 8], vals[pk & 0xFFu] * ew[p]);
            }
            __syncthreads();
            const float u = agg[t];
            if (nl == L) { vreg = tanhf(u); vals[t] = vreg; }
            agg[t] = 0.0f;
            if (L < 3) __syncthreads();
        }
        if (t >= NIN && t < NIN + NOUT)
            out[(size_t)b * NOUT + (t - NIN)] = vreg;
    } else {
        // ------- slow path (never taken on random data): reg-edge atomics -------
        float vreg = vals[t];
#pragma unroll
        for (int L = 1; L < 4; ++L) {
#define FB(J, CI, CO, W) \
            if (((keys >> (2*(J))) & 3u) == (unsigned)L) atomicAdd(&agg[(CO)], vals[(CI)] * (W));
            FB(0,  a0.x, c0.x, w0.x) FB(1,  a0.y, c0.y, w0.y)
            FB(2,  a0.z, c0.z, w0.z) FB(3,  a0.w, c0.w, w0.w)
            FB(4,  a1.x, c1.x, w1.x) FB(5,  a1.y, c1.y, w1.y)
            FB(6,  a1.z, c1.z, w1.z) FB(7,  a1.w, c1.w, w1.w)
            FB(8,  a2.x, c2.x, w2.x) FB(9,  a2.y, c2.y, w2.y)
            FB(10, a2.z, c2.z, w2.z) FB(11, a2.w, c2.w, w2.w)
            FB(12, a3.x, c3.x, w3.x) FB(13, a3.y, c3.y, w3.y)
            FB(14, a3.z, c3.z, w3.z) FB(15, a3.w, c3.w, w3.w)
#undef FB
            __syncthreads();
            const float u = agg[t];
            if (nl == L) { vreg = tanhf(u); vals[t] = vreg; }
            agg[t] = 0.0f;
            if (L < 3) __syncthreads();
        }
        if (t >= NIN && t < NIN + NOUT)
            out[(size_t)b * NOUT + (t - NIN)] = vreg;
    }
}

extern "C" void kernel_launch(void* const* d_in, const int* in_sizes, int n_in,
                              void* d_out, int out_size, void* d_ws, size_t ws_size,
                              hipStream_t stream) {
    const float* inputs          = (const float*)d_in[0];
    const int*   node_layer      = (const int*)d_in[1];
    const int*   conn_in         = (const int*)d_in[2];
    const int*   conn_out        = (const int*)d_in[3];
    const float* conn_w          = (const float*)d_in[4];
    const unsigned char* conn_en = (const unsigned char*)d_in[5];
    float* out = (float*)d_out;

    const int B = in_sizes[0] / NIN;   // 4096
    neat_fwd<<<B, NT, 0, stream>>>(inputs, node_layer, conn_in, conn_out,
                                   conn_w, conn_en, out);
}